// Round 5
// baseline (313.059 us; speedup 1.0000x reference)
//
#include <hip/hip_runtime.h>

typedef unsigned short u16;
typedef __attribute__((ext_vector_type(4))) float f32x4;
typedef __attribute__((ext_vector_type(8))) short short8;

#define WIN_SZ 100
#define NWIN 41
#define NBATCH 8
#define SEQ 4096
#define DM 512
#define NHEAD 8
#define KD 64
#define NWINS (NBATCH * NWIN)    // 328
#define MROWS (NWINS * WIN_SZ)   // 32800
#define MBLKS 257                // ceil(32800/128)
#define TOKPB (NWIN * WIN_SZ)    // 4100
#define NQKV 1536

// ws layout (u16 element offsets)
#define OFF_XBF   0u
#define OFF_OBUF  16793600u                 // + MROWS*DM
#define OFF_WQKVT 33587200u                 // + MROWS*DM
#define OFF_WOT   34373632u                 // + NQKV*DM
#define OFF_ZBLK  34635776u                 // + DM*DM
#define OFF_BIAS  34636032u                 // + 256   (1536 fp32 qkv bias)
#define OFF_BIAS2 34639104u                 // + 3072  (512 fp32 bo)

__device__ __forceinline__ u16 f2bf(float f) {
  union { float f; unsigned i; } v; v.f = f;
  unsigned r = (v.i + 0x7fffu + ((v.i >> 16) & 1u)) >> 16;
  return (u16)r;
}

// async global->LDS, 16B per lane; lds base wave-uniform (HW adds lane*16)
__device__ __forceinline__ void gl2lds16(const void* g, void* lds) {
  __builtin_amdgcn_global_load_lds(
      (const __attribute__((address_space(1))) void*)g,
      (__attribute__((address_space(3))) void*)lds, 16, 0, 0);
}

// ---------- prep: LDS-tiled 64x64 transposes (coalesced) + biases + zblk ----------
// z=0..2: Wq/Wk/Wv -> WqkvT rows [z*512, z*512+512); z=3: Wo -> WoT.
__global__ void prep_k(const float* __restrict__ Wq, const float* __restrict__ Wk,
                       const float* __restrict__ Wv, const float* __restrict__ Wo,
                       const float* __restrict__ bq, const float* __restrict__ bk,
                       const float* __restrict__ bv, const float* __restrict__ bo,
                       u16* __restrict__ ws) {
  __shared__ u16 tile[64][65];
  const int z = blockIdx.z;
  const float* src = (z == 0) ? Wq : (z == 1) ? Wk : (z == 2) ? Wv : Wo;
  u16* dst = (z < 3) ? (ws + OFF_WQKVT + (unsigned)z * 512u * 512u)
                     : (ws + OFF_WOT);
  const int k0 = blockIdx.y * 64, n0 = blockIdx.x * 64;
  const int t = threadIdx.x;
  const int c = t & 63, r4 = t >> 6;
#pragma unroll
  for (int p = 0; p < 16; ++p) {
    int r = p * 4 + r4;
    tile[r][c] = f2bf(src[(size_t)(k0 + r) * 512 + n0 + c]);
  }
  __syncthreads();
#pragma unroll
  for (int p = 0; p < 16; ++p) {
    int r = p * 4 + r4;                       // n index within tile
    dst[(size_t)(n0 + r) * 512 + k0 + c] = tile[c][r];
  }
  if (blockIdx.x == 0 && blockIdx.y == 0) {
    float* biasF = (float*)(ws + OFF_BIAS);
    float* biasO = (float*)(ws + OFF_BIAS2);
    for (int j = t; j < 512; j += 256) {
      if (z == 0) biasF[j] = bq[j];
      else if (z == 1) biasF[512 + j] = bk[j];
      else if (z == 2) biasF[1024 + j] = bv[j];
      else biasO[j] = bo[j];
    }
    if (z == 3 && t < 128) ws[OFF_ZBLK + t] = 0;
  }
}

// ---------------- x fp32 -> bf16 with window-padding gather ----------------
__global__ void convx_k(const float* __restrict__ x, u16* __restrict__ ws) {
  u16* xbf = ws + OFF_XBF;
  int i = blockIdx.x * 256 + threadIdx.x;     // float4-group index
  if (i >= MROWS * 128) return;
  int m = i >> 7;
  int c4 = (i & 127) * 4;
  int b = m / TOKPB, tk = m - b * TOKPB;
  float4 v = make_float4(0.f, 0.f, 0.f, 0.f);
  if (tk < SEQ) v = *(const float4*)(x + (size_t)(b * SEQ + tk) * DM + c4);
  u16 o[4] = {f2bf(v.x), f2bf(v.y), f2bf(v.z), f2bf(v.w)};
  *(uint2*)(xbf + (size_t)m * DM + c4) = *(const uint2*)o;
}

// -------------- fused QKV projection + attention, one block per (win, head) --------------
#define QKS 72   // Qs/Ks stride
#define PS 136   // P / Vt stride
// LDS (u16 elems): regionA [0,19456): phase1 Xs[112*64]+Wsl[192*64]; phase2+ Vt[64*136]
//                  regionB [19456,35584): phase2 Qs[112*72]+Ks[112*72]; phase3 P[112*136]
#define SM_ELEMS 35584

__global__ __launch_bounds__(256, 2)
void qkvattn_k(const u16* __restrict__ ws) {
  __shared__ u16 smem[SM_ELEMS];
  u16* Xs  = smem;              // 112 x 64
  u16* Wsl = smem + 7168;       // 192 x 64
  u16* Vt  = smem;              // 64 x 136 (reuses staging region)
  u16* Qs  = smem + 19456;      // 112 x 72
  u16* Ks  = smem + 19456 + 8064;
  u16* P   = smem + 19456;      // 112 x 136 (reuses Qs+Ks)

  const int win = blockIdx.x, h = blockIdx.y;
  const int t = threadIdx.x, w = t >> 6, l = t & 63;
  const int q = l >> 4, cl = l & 15;
  const int lc = (t & 7) * 8;

  // staging source offsets
  unsigned xoff[4];
#pragma unroll
  for (int i = 0; i < 4; ++i) {
    int m = i * 32 + (t >> 3);
    xoff[i] = (m < WIN_SZ)
                  ? (OFF_XBF + (unsigned)(win * WIN_SZ + m) * DM + lc)
                  : OFF_ZBLK;
  }
  unsigned woff[6];
#pragma unroll
  for (int i = 0; i < 6; ++i) {
    int g = i * 32 + (t >> 3);
    unsigned nrow = (unsigned)(g >> 6) * 512u + (unsigned)h * 64u + (g & 63);
    woff[i] = OFF_WQKVT + nrow * DM + lc;
  }

  // ---- phase 1: QKV projection. wave w owns n-tiles {3w,3w+1,3w+2} of 12 ----
  f32x4 acc_p[7][3] = {};
  for (int k0 = 0; k0 < DM; k0 += 64) {
    __syncthreads();
#pragma unroll
    for (int i = 0; i < 4; ++i)
      if (i * 32 + w * 8 < 112)   // wave-uniform
        gl2lds16(ws + xoff[i] + (xoff[i] == OFF_ZBLK ? 0u : (unsigned)k0),
                 &Xs[(i * 32 + w * 8) * 64]);
#pragma unroll
    for (int i = 0; i < 6; ++i)
      gl2lds16(ws + woff[i] + k0, &Wsl[(i * 32 + w * 8) * 64]);
    __syncthreads();
#pragma unroll
    for (int ks = 0; ks < 2; ++ks) {
      const int ko = ks * 32 + q * 8;
      short8 af[7], bf[3];
#pragma unroll
      for (int mt = 0; mt < 7; ++mt)
        af[mt] = *(const short8*)&Xs[(mt * 16 + cl) * 64 + ko];
#pragma unroll
      for (int ntl = 0; ntl < 3; ++ntl)
        bf[ntl] = *(const short8*)&Wsl[((3 * w + ntl) * 16 + cl) * 64 + ko];
#pragma unroll
      for (int mt = 0; mt < 7; ++mt)
#pragma unroll
        for (int ntl = 0; ntl < 3; ++ntl)
          acc_p[mt][ntl] = __builtin_amdgcn_mfma_f32_16x16x32_bf16(
              af[mt], bf[ntl], acc_p[mt][ntl], 0, 0, 0);
    }
  }
  __syncthreads();  // drain staging reads before Vt overwrites regionA

  // ---- phase 2: accs (+bias) -> Qs / Ks / Vt ----
  {
    const float* biasF = (const float*)(ws + OFF_BIAS);
#pragma unroll
    for (int ntl = 0; ntl < 3; ++ntl) {
      const int nt = 3 * w + ntl;
      const int cw = (nt & 3) * 16 + cl;               // col within Q/K/V
      const float bb = biasF[(nt >> 2) * 512 + h * 64 + cw];
#pragma unroll
      for (int mt = 0; mt < 7; ++mt)
#pragma unroll
        for (int r = 0; r < 4; ++r) {
          const int tok = mt * 16 + q * 4 + r;
          const u16 v16 = f2bf(acc_p[mt][ntl][r] + bb);
          if (nt < 4) Qs[tok * QKS + cw] = v16;
          else if (nt < 8) Ks[tok * QKS + cw] = v16;
          else Vt[cw * PS + tok] = v16;
        }
    }
    for (int idx = t; idx < 64 * 24; idx += 256)       // Vt cols 112..135 = 0
      Vt[(idx / 24) * PS + 112 + idx % 24] = 0;
  }
  __syncthreads();

  // ---- phase 3: S = Q K^T. wave w owns m-tiles {w, w+4} (wave 3: {3}) ----
  const int nmt = (w < 3) ? 2 : 1;
  const int mt0 = w, mt1 = w + 4;

  f32x4 accs[2][7];
#pragma unroll
  for (int im = 0; im < 2; ++im) {
    if (im < nmt) {
      const int mt = (im == 0) ? mt0 : mt1;
      const int ar = (mt * 16 + cl) * QKS + q * 8;
      short8 a0 = *(const short8*)&Qs[ar];
      short8 a1 = *(const short8*)&Qs[ar + 32];
#pragma unroll
      for (int nt = 0; nt < 7; ++nt) {
        const int br = (nt * 16 + cl) * QKS + q * 8;
        short8 b0 = *(const short8*)&Ks[br];
        short8 b1 = *(const short8*)&Ks[br + 32];
        f32x4 c = {};
        c = __builtin_amdgcn_mfma_f32_16x16x32_bf16(a0, b0, c, 0, 0, 0);
        c = __builtin_amdgcn_mfma_f32_16x16x32_bf16(a1, b1, c, 0, 0, 0);
        accs[im][nt] = c;
      }
    }
  }

  // softmax over cols 0..99 (100..111 masked), in registers
  const float scale = 0.125f;  // 1/sqrt(64)
#pragma unroll
  for (int im = 0; im < 2; ++im) {
    if (im < nmt) {
#pragma unroll
      for (int r = 0; r < 4; ++r) {
        float mx = -1e30f;
#pragma unroll
        for (int nt = 0; nt < 7; ++nt) {
          float s = accs[im][nt][r] * scale;
          if ((nt < 6) || (cl < 4)) mx = fmaxf(mx, s);
        }
        mx = fmaxf(mx, __shfl_xor(mx, 1, 64));
        mx = fmaxf(mx, __shfl_xor(mx, 2, 64));
        mx = fmaxf(mx, __shfl_xor(mx, 4, 64));
        mx = fmaxf(mx, __shfl_xor(mx, 8, 64));
        float sum = 0.f;
#pragma unroll
        for (int nt = 0; nt < 7; ++nt) {
          float s = accs[im][nt][r] * scale;
          bool valid = (nt < 6) || (cl < 4);
          float e = valid ? __expf(s - mx) : 0.f;
          accs[im][nt][r] = e;
          sum += e;
        }
        sum += __shfl_xor(sum, 1, 64);
        sum += __shfl_xor(sum, 2, 64);
        sum += __shfl_xor(sum, 4, 64);
        sum += __shfl_xor(sum, 8, 64);
        float inv = 1.0f / sum;
#pragma unroll
        for (int nt = 0; nt < 7; ++nt) accs[im][nt][r] *= inv;
      }
    }
  }
  __syncthreads();  // Qs/Ks reads drained before P overwrites regionB

  // ---- phase 4: P write + PV ----
#pragma unroll
  for (int im = 0; im < 2; ++im) {
    if (im < nmt) {
      const int mt = (im == 0) ? mt0 : mt1;
#pragma unroll
      for (int nt = 0; nt < 7; ++nt)
#pragma unroll
        for (int r = 0; r < 4; ++r)
          P[(mt * 16 + q * 4 + r) * PS + nt * 16 + cl] = f2bf(accs[im][nt][r]);
    }
  }
  for (int idx = t; idx < 112 * 24; idx += 256)        // P cols 112..135 = 0
    P[(idx / 24) * PS + 112 + idx % 24] = 0;
  __syncthreads();

  f32x4 acco[2][4] = {};
#pragma unroll
  for (int ks = 0; ks < 4; ++ks) {
    const int ko = ks * 32 + q * 8;
    short8 a0 = *(const short8*)&P[(mt0 * 16 + cl) * PS + ko];
    short8 a1 = a0;
    if (nmt == 2) a1 = *(const short8*)&P[(mt1 * 16 + cl) * PS + ko];
#pragma unroll
    for (int nt = 0; nt < 4; ++nt) {
      short8 b = *(const short8*)&Vt[(nt * 16 + cl) * PS + ko];
      acco[0][nt] = __builtin_amdgcn_mfma_f32_16x16x32_bf16(a0, b, acco[0][nt], 0, 0, 0);
      if (nmt == 2)
        acco[1][nt] = __builtin_amdgcn_mfma_f32_16x16x32_bf16(a1, b, acco[1][nt], 0, 0, 0);
    }
  }

  u16* obuf = (u16*)(ws + OFF_OBUF);
  const size_t orow0 = (size_t)win * WIN_SZ;
#pragma unroll
  for (int im = 0; im < 2; ++im) {
    if (im < nmt) {
      const int mt = (im == 0) ? mt0 : mt1;
#pragma unroll
      for (int nt = 0; nt < 4; ++nt)
#pragma unroll
        for (int r = 0; r < 4; ++r) {
          int row = mt * 16 + q * 4 + r;
          if (row < WIN_SZ)
            obuf[(orow0 + row) * DM + h * KD + nt * 16 + cl] = f2bf(acco[im][nt][r]);
        }
    }
  }
}

// ---------------- GEMM: C[M,N] = A[M,512] @ Bt[N,512]^T + bias (fp32 out) ----------------
__global__ __launch_bounds__(256, 4)
void gemm_k(const u16* __restrict__ ws, unsigned aoff0, unsigned btoff,
            unsigned biasoff, float* __restrict__ Cout, int Ntot) {
  __shared__ u16 Alds[128 * 64];
  __shared__ u16 Blds[128 * 64];

  const int t = threadIdx.x;
  const int w = t >> 6;
  const int l = t & 63;
  const int nb = blockIdx.x, mb = blockIdx.y;
  const int m0 = mb * 128, n0 = nb * 128;
  const int lr = t >> 3;
  const int lc = (t & 7) * 8;

  unsigned aoff[4], boff[4];
#pragma unroll
  for (int i = 0; i < 4; ++i) {
    int m = m0 + i * 32 + lr;
    aoff[i] = (m < MROWS) ? (aoff0 + (unsigned)m * DM + lc) : OFF_ZBLK;
    boff[i] = btoff + (unsigned)(n0 + i * 32 + lr) * DM + lc;
  }

  f32x4 acc[4][4] = {};
  const int wm = (w & 1) * 64;
  const int wn = (w >> 1) * 64;
  const int q = l >> 4, cl = l & 15;

  for (int k0 = 0; k0 < DM; k0 += 64) {
    __syncthreads();
#pragma unroll
    for (int i = 0; i < 4; ++i) {
      gl2lds16(ws + aoff[i] + (aoff[i] == OFF_ZBLK ? 0u : (unsigned)k0),
               &Alds[(i * 32 + w * 8) * 64]);
      gl2lds16(ws + boff[i] + k0, &Blds[(i * 32 + w * 8) * 64]);
    }
    __syncthreads();
#pragma unroll
    for (int ks = 0; ks < 2; ++ks) {
      short8 av[4], bv_[4];
      const int ko = ks * 32 + q * 8;
#pragma unroll
      for (int mi = 0; mi < 4; ++mi)
        av[mi] = *(const short8*)&Alds[(wm + mi * 16 + cl) * 64 + ko];
#pragma unroll
      for (int ni = 0; ni < 4; ++ni)
        bv_[ni] = *(const short8*)&Blds[(wn + ni * 16 + cl) * 64 + ko];
#pragma unroll
      for (int mi = 0; mi < 4; ++mi)
#pragma unroll
        for (int ni = 0; ni < 4; ++ni)
          acc[mi][ni] = __builtin_amdgcn_mfma_f32_16x16x32_bf16(
              av[mi], bv_[ni], acc[mi][ni], 0, 0, 0);
    }
  }

  const float* biasF = (const float*)(ws + biasoff);
#pragma unroll
  for (int mi = 0; mi < 4; ++mi) {
#pragma unroll
    for (int ni = 0; ni < 4; ++ni) {
      int col = n0 + wn + ni * 16 + cl;
      float bb = biasF[col];
#pragma unroll
      for (int r = 0; r < 4; ++r) {
        int row = m0 + wm + mi * 16 + q * 4 + r;
        if (row < MROWS)
          Cout[(size_t)row * Ntot + col] = acc[mi][ni][r] + bb;
      }
    }
  }
}

extern "C" void kernel_launch(void* const* d_in, const int* in_sizes, int n_in,
                              void* d_out, int out_size, void* d_ws, size_t ws_size,
                              hipStream_t stream) {
  const float* x  = (const float*)d_in[0];
  const float* Wq = (const float*)d_in[1];
  const float* bq = (const float*)d_in[2];
  const float* Wk = (const float*)d_in[3];
  const float* bk = (const float*)d_in[4];
  const float* Wv = (const float*)d_in[5];
  const float* bv = (const float*)d_in[6];
  const float* Wo = (const float*)d_in[7];
  const float* bo = (const float*)d_in[8];

  u16* ws = (u16*)d_ws;

  prep_k<<<dim3(8, 8, 4), dim3(256), 0, stream>>>(
      Wq, Wk, Wv, Wo, bq, bk, bv, bo, ws);
  convx_k<<<dim3((MROWS * 128 + 255) / 256), dim3(256), 0, stream>>>(x, ws);
  qkvattn_k<<<dim3(NWINS, NHEAD), dim3(256), 0, stream>>>(ws);
  gemm_k<<<dim3(DM / 128, MBLKS), dim3(256), 0, stream>>>(
      ws, OFF_OBUF, OFF_WOT, OFF_BIAS2, (float*)d_out, DM);
}

// Round 6
// 283.491 us; speedup vs baseline: 1.1043x; 1.1043x over previous
//
#include <hip/hip_runtime.h>

typedef unsigned short u16;
typedef __attribute__((ext_vector_type(4))) float f32x4;
typedef __attribute__((ext_vector_type(8))) short short8;

#define WIN_SZ 100
#define NWIN 41
#define NBATCH 8
#define SEQ 4096
#define DM 512
#define NHEAD 8
#define KD 64
#define NWINS (NBATCH * NWIN)    // 328
#define MROWS (NWINS * WIN_SZ)   // 32800
#define MBLKS 257                // ceil(32800/128)
#define TOKPB (NWIN * WIN_SZ)    // 4100
#define NQKV 1536

// ws layout (u16 element offsets)
#define OFF_XBF   0u
#define OFF_OBUF  16793600u                 // + MROWS*DM
#define OFF_WQKVT 33587200u                 // + MROWS*DM
#define OFF_WOT   34373632u                 // + NQKV*DM
#define OFF_ZBLK  34635776u                 // + DM*DM
#define OFF_BIAS  34636032u                 // + 256   (1536 fp32 qkv bias)
#define OFF_BIAS2 34639104u                 // + 3072  (512 fp32 bo)

__device__ __forceinline__ u16 f2bf(float f) {
  union { float f; unsigned i; } v; v.f = f;
  unsigned r = (v.i + 0x7fffu + ((v.i >> 16) & 1u)) >> 16;
  return (u16)r;
}

// async global->LDS, 16B per lane; lds base wave-uniform (HW adds lane*16)
__device__ __forceinline__ void gl2lds16(const void* g, void* lds) {
  __builtin_amdgcn_global_load_lds(
      (const __attribute__((address_space(1))) void*)g,
      (__attribute__((address_space(3))) void*)lds, 16, 0, 0);
}

// ---------- prep: LDS-tiled 64x64 transposes (coalesced) + biases + zblk ----------
// z=0..2: Wq/Wk/Wv -> WqkvT rows [z*512, z*512+512); z=3: Wo -> WoT.
__global__ void prep_k(const float* __restrict__ Wq, const float* __restrict__ Wk,
                       const float* __restrict__ Wv, const float* __restrict__ Wo,
                       const float* __restrict__ bq, const float* __restrict__ bk,
                       const float* __restrict__ bv, const float* __restrict__ bo,
                       u16* __restrict__ ws) {
  __shared__ u16 tile[64][65];
  const int z = blockIdx.z;
  const float* src = (z == 0) ? Wq : (z == 1) ? Wk : (z == 2) ? Wv : Wo;
  u16* dst = (z < 3) ? (ws + OFF_WQKVT + (unsigned)z * 512u * 512u)
                     : (ws + OFF_WOT);
  const int k0 = blockIdx.y * 64, n0 = blockIdx.x * 64;
  const int t = threadIdx.x;
  const int c = t & 63, r4 = t >> 6;
#pragma unroll
  for (int p = 0; p < 16; ++p) {
    int r = p * 4 + r4;
    tile[r][c] = f2bf(src[(size_t)(k0 + r) * 512 + n0 + c]);
  }
  __syncthreads();
#pragma unroll
  for (int p = 0; p < 16; ++p) {
    int r = p * 4 + r4;                       // n index within tile
    dst[(size_t)(n0 + r) * 512 + k0 + c] = tile[c][r];
  }
  if (blockIdx.x == 0 && blockIdx.y == 0) {
    float* biasF = (float*)(ws + OFF_BIAS);
    float* biasO = (float*)(ws + OFF_BIAS2);
    for (int j = t; j < 512; j += 256) {
      if (z == 0) biasF[j] = bq[j];
      else if (z == 1) biasF[512 + j] = bk[j];
      else if (z == 2) biasF[1024 + j] = bv[j];
      else biasO[j] = bo[j];
    }
    if (z == 3 && t < 128) ws[OFF_ZBLK + t] = 0;
  }
}

// ---------------- x fp32 -> bf16 with window-padding gather ----------------
__global__ void convx_k(const float* __restrict__ x, u16* __restrict__ ws) {
  u16* xbf = ws + OFF_XBF;
  int i = blockIdx.x * 256 + threadIdx.x;     // float4-group index
  if (i >= MROWS * 128) return;
  int m = i >> 7;
  int c4 = (i & 127) * 4;
  int b = m / TOKPB, tk = m - b * TOKPB;
  float4 v = make_float4(0.f, 0.f, 0.f, 0.f);
  if (tk < SEQ) v = *(const float4*)(x + (size_t)(b * SEQ + tk) * DM + c4);
  u16 o[4] = {f2bf(v.x), f2bf(v.y), f2bf(v.z), f2bf(v.w)};
  *(uint2*)(xbf + (size_t)m * DM + c4) = *(const uint2*)o;
}

// -------------- fused QKV projection + attention, one block per (win, head) --------------
#define QKS 72   // Qs/Ks stride
#define PS 136   // P / Vt stride
// LDS phase-union (u16 elems), total 24832 (49664 B -> 3 blocks/CU):
//   phase1 (staging, dies at post-loop barrier): Xs [0,7168) + Wsl [7168,19456)
//   phase2+: Vt [0,8704) | Qs [8704,16768) | Ks [16768,24832)
//   phase4:  P  [8704,23936) overlays Qs+Ks
#define SM_ELEMS 24832

__global__ __launch_bounds__(256, 3)
void qkvattn_k(const u16* __restrict__ ws) {
  __shared__ u16 smem[SM_ELEMS];
  u16* Xs  = smem;              // 112 x 64
  u16* Wsl = smem + 7168;       // 192 x 64
  u16* Vt  = smem;              // 64 x 136
  u16* Qs  = smem + 8704;       // 112 x 72
  u16* Ks  = smem + 16768;      // 112 x 72
  u16* P   = smem + 8704;       // 112 x 136

  const int win = blockIdx.x, h = blockIdx.y;
  const int t = threadIdx.x, w = t >> 6, l = t & 63;
  const int q = l >> 4, cl = l & 15;
  const int lc = (t & 7) * 8;

  // staging source offsets
  unsigned xoff[4];
#pragma unroll
  for (int i = 0; i < 4; ++i) {
    int m = i * 32 + (t >> 3);
    xoff[i] = (m < WIN_SZ)
                  ? (OFF_XBF + (unsigned)(win * WIN_SZ + m) * DM + lc)
                  : OFF_ZBLK;
  }
  unsigned woff[6];
#pragma unroll
  for (int i = 0; i < 6; ++i) {
    int g = i * 32 + (t >> 3);
    unsigned nrow = (unsigned)(g >> 6) * 512u + (unsigned)h * 64u + (g & 63);
    woff[i] = OFF_WQKVT + nrow * DM + lc;
  }

  // ---- phase 1: QKV projection. wave w owns n-tiles {3w,3w+1,3w+2} of 12 ----
  f32x4 acc_p[7][3] = {};
  for (int k0 = 0; k0 < DM; k0 += 64) {
    __syncthreads();
#pragma unroll
    for (int i = 0; i < 4; ++i)
      if (i * 32 + w * 8 < 112)   // wave-uniform
        gl2lds16(ws + xoff[i] + (xoff[i] == OFF_ZBLK ? 0u : (unsigned)k0),
                 &Xs[(i * 32 + w * 8) * 64]);
#pragma unroll
    for (int i = 0; i < 6; ++i)
      gl2lds16(ws + woff[i] + k0, &Wsl[(i * 32 + w * 8) * 64]);
    __syncthreads();
#pragma unroll
    for (int ks = 0; ks < 2; ++ks) {
      const int ko = ks * 32 + q * 8;
      short8 af[7], bf[3];
#pragma unroll
      for (int mt = 0; mt < 7; ++mt)
        af[mt] = *(const short8*)&Xs[(mt * 16 + cl) * 64 + ko];
#pragma unroll
      for (int ntl = 0; ntl < 3; ++ntl)
        bf[ntl] = *(const short8*)&Wsl[((3 * w + ntl) * 16 + cl) * 64 + ko];
#pragma unroll
      for (int mt = 0; mt < 7; ++mt)
#pragma unroll
        for (int ntl = 0; ntl < 3; ++ntl)
          acc_p[mt][ntl] = __builtin_amdgcn_mfma_f32_16x16x32_bf16(
              af[mt], bf[ntl], acc_p[mt][ntl], 0, 0, 0);
    }
  }
  __syncthreads();  // staging reads drained; Vt/Qs/Ks may now overwrite

  // ---- phase 2: accs (+bias) -> Qs / Ks / Vt ----
  {
    const float* biasF = (const float*)(ws + OFF_BIAS);
#pragma unroll
    for (int ntl = 0; ntl < 3; ++ntl) {
      const int nt = 3 * w + ntl;
      const int cw = (nt & 3) * 16 + cl;               // col within Q/K/V
      const float bb = biasF[(nt >> 2) * 512 + h * 64 + cw];
#pragma unroll
      for (int mt = 0; mt < 7; ++mt)
#pragma unroll
        for (int r = 0; r < 4; ++r) {
          const int tok = mt * 16 + q * 4 + r;
          const u16 v16 = f2bf(acc_p[mt][ntl][r] + bb);
          if (nt < 4) Qs[tok * QKS + cw] = v16;
          else if (nt < 8) Ks[tok * QKS + cw] = v16;
          else Vt[cw * PS + tok] = v16;
        }
    }
    for (int idx = t; idx < 64 * 24; idx += 256)       // Vt cols 112..135 = 0
      Vt[(idx / 24) * PS + 112 + idx % 24] = 0;
  }
  __syncthreads();

  // ---- phase 3: S = Q K^T. wave w owns m-tiles {w, w+4} (wave 3: {3}) ----
  const int nmt = (w < 3) ? 2 : 1;
  const int mt0 = w, mt1 = w + 4;

  f32x4 accs[2][7];
#pragma unroll
  for (int im = 0; im < 2; ++im) {
    if (im < nmt) {
      const int mt = (im == 0) ? mt0 : mt1;
      const int ar = (mt * 16 + cl) * QKS + q * 8;
      short8 a0 = *(const short8*)&Qs[ar];
      short8 a1 = *(const short8*)&Qs[ar + 32];
#pragma unroll
      for (int nt = 0; nt < 7; ++nt) {
        const int br = (nt * 16 + cl) * QKS + q * 8;
        short8 b0 = *(const short8*)&Ks[br];
        short8 b1 = *(const short8*)&Ks[br + 32];
        f32x4 c = {};
        c = __builtin_amdgcn_mfma_f32_16x16x32_bf16(a0, b0, c, 0, 0, 0);
        c = __builtin_amdgcn_mfma_f32_16x16x32_bf16(a1, b1, c, 0, 0, 0);
        accs[im][nt] = c;
      }
    }
  }

  // softmax over cols 0..99 (100..111 masked), in registers
  const float scale = 0.125f;  // 1/sqrt(64)
#pragma unroll
  for (int im = 0; im < 2; ++im) {
    if (im < nmt) {
#pragma unroll
      for (int r = 0; r < 4; ++r) {
        float mx = -1e30f;
#pragma unroll
        for (int nt = 0; nt < 7; ++nt) {
          float s = accs[im][nt][r] * scale;
          if ((nt < 6) || (cl < 4)) mx = fmaxf(mx, s);
        }
        mx = fmaxf(mx, __shfl_xor(mx, 1, 64));
        mx = fmaxf(mx, __shfl_xor(mx, 2, 64));
        mx = fmaxf(mx, __shfl_xor(mx, 4, 64));
        mx = fmaxf(mx, __shfl_xor(mx, 8, 64));
        float sum = 0.f;
#pragma unroll
        for (int nt = 0; nt < 7; ++nt) {
          float s = accs[im][nt][r] * scale;
          bool valid = (nt < 6) || (cl < 4);
          float e = valid ? __expf(s - mx) : 0.f;
          accs[im][nt][r] = e;
          sum += e;
        }
        sum += __shfl_xor(sum, 1, 64);
        sum += __shfl_xor(sum, 2, 64);
        sum += __shfl_xor(sum, 4, 64);
        sum += __shfl_xor(sum, 8, 64);
        float inv = 1.0f / sum;
#pragma unroll
        for (int nt = 0; nt < 7; ++nt) accs[im][nt][r] *= inv;
      }
    }
  }
  __syncthreads();  // Qs/Ks reads drained before P overwrites them

  // ---- phase 4: P write + PV ----
#pragma unroll
  for (int im = 0; im < 2; ++im) {
    if (im < nmt) {
      const int mt = (im == 0) ? mt0 : mt1;
#pragma unroll
      for (int nt = 0; nt < 7; ++nt)
#pragma unroll
        for (int r = 0; r < 4; ++r)
          P[(mt * 16 + q * 4 + r) * PS + nt * 16 + cl] = f2bf(accs[im][nt][r]);
    }
  }
  for (int idx = t; idx < 112 * 24; idx += 256)        // P cols 112..135 = 0
    P[(idx / 24) * PS + 112 + idx % 24] = 0;
  __syncthreads();

  f32x4 acco[2][4] = {};
#pragma unroll
  for (int ks = 0; ks < 4; ++ks) {
    const int ko = ks * 32 + q * 8;
    short8 a0 = *(const short8*)&P[(mt0 * 16 + cl) * PS + ko];
    short8 a1 = a0;
    if (nmt == 2) a1 = *(const short8*)&P[(mt1 * 16 + cl) * PS + ko];
#pragma unroll
    for (int nt = 0; nt < 4; ++nt) {
      short8 b = *(const short8*)&Vt[(nt * 16 + cl) * PS + ko];
      acco[0][nt] = __builtin_amdgcn_mfma_f32_16x16x32_bf16(a0, b, acco[0][nt], 0, 0, 0);
      if (nmt == 2)
        acco[1][nt] = __builtin_amdgcn_mfma_f32_16x16x32_bf16(a1, b, acco[1][nt], 0, 0, 0);
    }
  }

  u16* obuf = (u16*)(ws + OFF_OBUF);
  const size_t orow0 = (size_t)win * WIN_SZ;
#pragma unroll
  for (int im = 0; im < 2; ++im) {
    if (im < nmt) {
      const int mt = (im == 0) ? mt0 : mt1;
#pragma unroll
      for (int nt = 0; nt < 4; ++nt)
#pragma unroll
        for (int r = 0; r < 4; ++r) {
          int row = mt * 16 + q * 4 + r;
          if (row < WIN_SZ)
            obuf[(orow0 + row) * DM + h * KD + nt * 16 + cl] = f2bf(acco[im][nt][r]);
        }
    }
  }
}

// ---------------- GEMM: C[M,N] = A[M,512] @ Bt[N,512]^T + bias (fp32 out) ----------------
__global__ __launch_bounds__(256, 4)
void gemm_k(const u16* __restrict__ ws, unsigned aoff0, unsigned btoff,
            unsigned biasoff, float* __restrict__ Cout, int Ntot) {
  __shared__ u16 Alds[128 * 64];
  __shared__ u16 Blds[128 * 64];

  const int t = threadIdx.x;
  const int w = t >> 6;
  const int l = t & 63;
  const int nb = blockIdx.x, mb = blockIdx.y;
  const int m0 = mb * 128, n0 = nb * 128;
  const int lr = t >> 3;
  const int lc = (t & 7) * 8;

  unsigned aoff[4], boff[4];
#pragma unroll
  for (int i = 0; i < 4; ++i) {
    int m = m0 + i * 32 + lr;
    aoff[i] = (m < MROWS) ? (aoff0 + (unsigned)m * DM + lc) : OFF_ZBLK;
    boff[i] = btoff + (unsigned)(n0 + i * 32 + lr) * DM + lc;
  }

  f32x4 acc[4][4] = {};
  const int wm = (w & 1) * 64;
  const int wn = (w >> 1) * 64;
  const int q = l >> 4, cl = l & 15;

  for (int k0 = 0; k0 < DM; k0 += 64) {
    __syncthreads();
#pragma unroll
    for (int i = 0; i < 4; ++i) {
      gl2lds16(ws + aoff[i] + (aoff[i] == OFF_ZBLK ? 0u : (unsigned)k0),
               &Alds[(i * 32 + w * 8) * 64]);
      gl2lds16(ws + boff[i] + k0, &Blds[(i * 32 + w * 8) * 64]);
    }
    __syncthreads();
#pragma unroll
    for (int ks = 0; ks < 2; ++ks) {
      short8 av[4], bv_[4];
      const int ko = ks * 32 + q * 8;
#pragma unroll
      for (int mi = 0; mi < 4; ++mi)
        av[mi] = *(const short8*)&Alds[(wm + mi * 16 + cl) * 64 + ko];
#pragma unroll
      for (int ni = 0; ni < 4; ++ni)
        bv_[ni] = *(const short8*)&Blds[(wn + ni * 16 + cl) * 64 + ko];
#pragma unroll
      for (int mi = 0; mi < 4; ++mi)
#pragma unroll
        for (int ni = 0; ni < 4; ++ni)
          acc[mi][ni] = __builtin_amdgcn_mfma_f32_16x16x32_bf16(
              av[mi], bv_[ni], acc[mi][ni], 0, 0, 0);
    }
  }

  const float* biasF = (const float*)(ws + biasoff);
#pragma unroll
  for (int mi = 0; mi < 4; ++mi) {
#pragma unroll
    for (int ni = 0; ni < 4; ++ni) {
      int col = n0 + wn + ni * 16 + cl;
      float bb = biasF[col];
#pragma unroll
      for (int r = 0; r < 4; ++r) {
        int row = m0 + wm + mi * 16 + q * 4 + r;
        if (row < MROWS)
          Cout[(size_t)row * Ntot + col] = acc[mi][ni][r] + bb;
      }
    }
  }
}

extern "C" void kernel_launch(void* const* d_in, const int* in_sizes, int n_in,
                              void* d_out, int out_size, void* d_ws, size_t ws_size,
                              hipStream_t stream) {
  const float* x  = (const float*)d_in[0];
  const float* Wq = (const float*)d_in[1];
  const float* bq = (const float*)d_in[2];
  const float* Wk = (const float*)d_in[3];
  const float* bk = (const float*)d_in[4];
  const float* Wv = (const float*)d_in[5];
  const float* bv = (const float*)d_in[6];
  const float* Wo = (const float*)d_in[7];
  const float* bo = (const float*)d_in[8];

  u16* ws = (u16*)d_ws;

  prep_k<<<dim3(8, 8, 4), dim3(256), 0, stream>>>(
      Wq, Wk, Wv, Wo, bq, bk, bv, bo, ws);
  convx_k<<<dim3((MROWS * 128 + 255) / 256), dim3(256), 0, stream>>>(x, ws);
  qkvattn_k<<<dim3(NWINS, NHEAD), dim3(256), 0, stream>>>(ws);
  gemm_k<<<dim3(DM / 128, MBLKS), dim3(256), 0, stream>>>(
      ws, OFF_OBUF, OFF_WOT, OFF_BIAS2, (float*)d_out, DM);
}